// Round 5
// baseline (792.741 us; speedup 1.0000x reference)
//
#include <hip/hip_runtime.h>

// CTC-like forward scan — single wave per batch element, all-register state.
// R5: per-step loop is pure FMA + direct per-lane global loads of exp(x)
// (prepass), one pipelined __shfl_up for the lane boundary. Exponent-frame
// alignment (per-lane power-of-2 offset M) hoisted to once per 8 steps.
//
// Lane l owns positions 8l+1..8l+8 (F[0..7]); lane 0 also owns position 0
// (F0 with its own exponent M0). True value = F * 2^M.
// new[p] = fwd[p]*S + fwd[p-1]*V_p,  V_p = exp(x[t][b][seqs[p-1]]), S = exp(x4).

#define TT 4096
#define BB 64
#define PP 512
#define LN2F 0.69314718055994531f
#define ROWB (BB * 5 * 4)   // 1280 bytes per t-row

__global__ __launch_bounds__(256, 1)
void ctc_prepass(const float* __restrict__ x, float* __restrict__ xpow) {
    int j = blockIdx.x * blockDim.x + threadIdx.x;   // over T*B*5
    if (j < TT * BB * 5) xpow[j] = __expf(x[j]);
}

__global__ __launch_bounds__(64, 1)
void ctc_scan(const float* __restrict__ xpow, const int* __restrict__ seqs,
              const int* __restrict__ seqlens, float* __restrict__ out) {
    __shared__ float garr[PP + 1];

    const int b = blockIdx.x;
    const int l = threadIdx.x;                    // 0..63
    const bool lane0 = (l == 0);

    // byte offsets within a 20B (t,b)-row for this lane's 8 move features
    int voff[8];
#pragma unroll
    for (int i = 0; i < 8; ++i)
        voff[i] = seqs[b * PP + 8 * l + i] << 2;

    const char* xrow0 = (const char*)xpow + (size_t)b * 20;

    float F[8];
#pragma unroll
    for (int i = 0; i < 8; ++i) F[i] = 0.0f;
    float F0 = lane0 ? 1.0f : 0.0f;
    int M = 0, M0 = 0;

    // 4-step-deep register ring of V/S values
    float Vr[4][8], Sr[4];
#pragma unroll
    for (int s = 0; s < 4; ++s) {
        const char* rp = xrow0 + (size_t)s * ROWB;
        Sr[s] = *(const float*)(rp + 16);
#pragma unroll
        for (int i = 0; i < 8; ++i)
            Vr[s][i] = *(const float*)(rp + voff[i]);
    }

    float Fl_pend = 0.0f;

    for (int tb = 0; tb < TT; tb += 8) {
        // ---- block start: renorm + frame exchange + scale-factor prep ----
        {
            float m = F[0];
#pragma unroll
            for (int i = 1; i < 8; ++i) m = fmaxf(m, F[i]);
            int e2 = ((__float_as_int(m) >> 23) & 0xFF) - 127;
            e2 = (m > 0.0f) ? e2 : 0;
#pragma unroll
            for (int i = 0; i < 8; ++i) F[i] = ldexpf(F[i], -e2);
            M += e2;
            int e0 = ((__float_as_int(F0) >> 23) & 0xFF) - 127;
            e0 = (F0 > 0.0f) ? e0 : 0;
            F0 = ldexpf(F0, -e0);
            M0 += e0;
        }
        int Ml = __shfl_up(M, 1, 64);
        Fl_pend = __shfl_up(F[7], 1, 64);         // post-renorm neighbor value
        int dl = lane0 ? (M0 - M) : (Ml - M);
        if (dl > 0) {                              // down-only self-squash
#pragma unroll
            for (int i = 0; i < 8; ++i) F[i] = ldexpf(F[i], -dl);
            M += dl;
        }
        int dn = lane0 ? 0 : (Ml - M);  if (dn > 0) dn = 0;
        int d0 = M0 - M;                if (d0 > 0) d0 = 0;
        const float sfac = ldexpf(1.0f, dn);       // incoming-from-left scale
        const float sf0  = ldexpf(1.0f, d0);       // lane0: incoming-from-F0 scale
        const float sA   = lane0 ? sf0 : sfac;

        // ---- 8 steps, fully unrolled ----
#pragma unroll
        for (int u = 0; u < 8; ++u) {
            const int slot = u & 3;
            const float S = Sr[slot];
            float V[8];
#pragma unroll
            for (int i = 0; i < 8; ++i) V[i] = Vr[slot][i];

            const float fin = lane0 ? F0 : Fl_pend;
            const float adj = fin * sA;

            // F[7] first, then pipeline the boundary shuffle for next step
            F[7] = fmaf(F[7], S, F[6] * V[7]);
            const float Fl_new = __shfl_up(F[7], 1, 64);
#pragma unroll
            for (int i = 6; i >= 1; --i)
                F[i] = fmaf(F[i], S, F[i - 1] * V[i]);
            F[0] = fmaf(F[0], S, adj * V[0]);
            F0 *= S;
            Fl_pend = Fl_new;

            // refill ring slot with row tb+u+4 (clamped; surplus unused)
            int tr = tb + u + 4; if (tr > TT - 1) tr = TT - 1;
            const char* rp = xrow0 + (size_t)tr * ROWB;
            Sr[slot] = *(const float*)(rp + 16);
#pragma unroll
            for (int i = 0; i < 8; ++i)
                Vr[slot][i] = *(const float*)(rp + voff[i]);
        }
    }

    // epilogue: log2 reconstruction (denormal-safe: scale by 2^24 first)
#pragma unroll
    for (int i = 0; i < 8; ++i) {
        float v = fmaxf(F[i] * 16777216.0f, 1e-38f);
        garr[8 * l + 1 + i] = __log2f(v) - 24.0f + (float)M;
    }
    if (lane0) {
        float v0 = fmaxf(F0 * 16777216.0f, 1e-38f);
        garr[0] = __log2f(v0) - 24.0f + (float)M0;
    }
    __syncthreads();
    if (lane0) {
        int sl = seqlens[b];
        out[b] = -(garr[sl] * LN2F) / (float)TT;
    }
}

extern "C" void kernel_launch(void* const* d_in, const int* in_sizes, int n_in,
                              void* d_out, int out_size, void* d_ws, size_t ws_size,
                              hipStream_t stream) {
    const float* x       = (const float*)d_in[0];
    const int*   seqs    = (const int*)d_in[1];
    const int*   seqlens = (const int*)d_in[2];
    float*       out     = (float*)d_out;
    float*       xpow    = (float*)d_ws;          // TT*BB*5 floats = 5.25 MB

    int n = TT * BB * 5;
    ctc_prepass<<<(n + 255) / 256, 256, 0, stream>>>(x, xpow);
    ctc_scan<<<BB, 64, 0, stream>>>(xpow, seqs, seqlens, out);
}

// Round 7
// 505.206 us; speedup vs baseline: 1.5691x; 1.5691x over previous
//
#include <hip/hip_runtime.h>

// CTC-like forward scan. R7: single wave per batch element, all-register F.
// - Prepass transposes+exps x into xT[b][t][8] (padded 32B rows): per-block
//   data contiguous (128 KB per block).
// - Async global->LDS staging (global_load_lds, 16B wide) of 64-row chunks,
//   8-slot LDS ring, staged 4 chunks (=256 steps) ahead; one explicit
//   s_waitcnt vmcnt(6) per chunk. Side-effecting intrinsic => compiler cannot
//   collapse the prefetch (the R4/R5 failure mode: register-ring prefetches
//   were sunk to use sites, exposing full L2 latency every step).
// - Per step: 9 ds_read_b32 gathers (prefetched 1 step ahead; seqs in [0,4)
//   => <=5 distinct words per row => conflict-free), 17 FMA/mul, boundary via
//   __shfl_up pipelined one step ahead of its consumer.
// - Exponent frames (per-lane M, down-only alignment, renorm every 8 steps)
//   identical to the R5 kernel that passed with absmax 0.0.

#define TT 4096
#define BB 64
#define PP 512
#define LN2F 0.69314718055994531f

__global__ __launch_bounds__(256, 1)
void ctc_prepass(const float* __restrict__ x, float* __restrict__ xT) {
    int j = blockIdx.x * blockDim.x + threadIdx.x;   // over T*B*5
    if (j >= TT * BB * 5) return;
    int row = j / 5, f = j - row * 5;                // row = t*64 + b
    int t = row >> 6, b = row & 63;
    xT[(((size_t)b * TT + t) << 3) + f] = __expf(x[j]);
}

__device__ __forceinline__ void gload_lds16(const void* g, void* l) {
    auto gp = (const __attribute__((address_space(1))) void*)(uintptr_t)g;
    auto lp = (__attribute__((address_space(3))) void*)(uintptr_t)l;   // low 32b = LDS offset
    __builtin_amdgcn_global_load_lds(gp, lp, 16, 0, 0);
}

__global__ __launch_bounds__(64, 1)
void ctc_scan(const float* __restrict__ xT, const int* __restrict__ seqs,
              const int* __restrict__ seqlens, float* __restrict__ out) {
    __shared__ __align__(16) float ring[4096];       // 16 KB: 8 chunks x 64 rows x 32 B
    __shared__ float garr[PP + 1];

    const int b = blockIdx.x;
    const int l = threadIdx.x;                       // 0..63
    const bool lane0 = (l == 0);

    int voff[8];
#pragma unroll
    for (int i = 0; i < 8; ++i)
        voff[i] = seqs[b * PP + 8 * l + i] << 2;     // byte offset in 32B row

    const char* srcb = (const char*)(xT + ((size_t)b * TT << 3));
    char* ringb = (char*)ring;

    // ---- stage chunks 0..3 (8 async 16B loads; 2048 B per chunk) ----
#pragma unroll
    for (int c0 = 0; c0 < 4; ++c0) {
        const char* g = srcb + c0 * 2048;
        char* lb = ringb + c0 * 2048;
        gload_lds16(g + l * 16, lb + l * 16);
        gload_lds16(g + 1024 + l * 16, lb + 1024 + l * 16);
    }
    asm volatile("s_waitcnt vmcnt(6)" ::: "memory"); // chunk 0 resident

    float F[8];
#pragma unroll
    for (int i = 0; i < 8; ++i) F[i] = 0.0f;
    float F0 = lane0 ? 1.0f : 0.0f;
    int M = 0, M0 = 0;
    float Fl = 0.0f, sA = 1.0f, sf0 = 1.0f;
    unsigned rowoff = 0;

    // gather double-buffer: rows t and t+1 (8 V values + S each)
    float ga[9], gb[9];
    {
        const char* rp = ringb;                      // row 0
        ga[8] = *(const float*)(rp + 16);
#pragma unroll
        for (int i = 0; i < 8; ++i)
            ga[i] = *(const float*)(rp + voff[i]);
    }

    auto do_step = [&](const float (&gc)[9], float (&gn)[9]) {
        // prefetch next row's gathers first (latency overlaps this step's FMAs)
        rowoff = (rowoff + 32u) & 16383u;
        const char* rp = ringb + rowoff;
        gn[8] = *(const float*)(rp + 16);
#pragma unroll
        for (int i = 0; i < 8; ++i)
            gn[i] = *(const float*)(rp + voff[i]);

        const float S = gc[8];
        const float fin = lane0 ? F0 * sf0 : Fl * sA;
        F[7] = fmaf(F[7], S, F[6] * gc[7]);
        const float F7n = F[7];
#pragma unroll
        for (int i = 6; i >= 1; --i)
            F[i] = fmaf(F[i], S, F[i - 1] * gc[i]);
        F[0] = fmaf(F[0], S, fin * gc[0]);
        F0 *= S;
        Fl = __shfl_up(F7n, 1, 64);                  // boundary for next step
    };

    for (int c = 0; c < 64; ++c) {
        // stage chunk c+4 (clamped duplicate keeps vmcnt bookkeeping constant)
        {
            int cs = (c + 4 > 63) ? 63 : (c + 4);
            const char* g = srcb + cs * 2048;
            char* lb = ringb + ((c + 4) & 7) * 2048;
            gload_lds16(g + l * 16, lb + l * 16);
            gload_lds16(g + 1024 + l * 16, lb + 1024 + l * 16);
        }
        asm volatile("s_waitcnt vmcnt(6)" ::: "memory");  // chunk c+1 resident

        for (int r8 = 0; r8 < 8; ++r8) {
            // ---- renorm + frame exchange (once per 8 steps; R5-validated) ----
            float m = F[0];
#pragma unroll
            for (int i = 1; i < 8; ++i) m = fmaxf(m, F[i]);
            int e2 = ((__float_as_int(m) >> 23) & 0xFF) - 127;
            e2 = (m > 0.0f) ? e2 : 0;
#pragma unroll
            for (int i = 0; i < 8; ++i) F[i] = ldexpf(F[i], -e2);
            M += e2;
            int e0 = ((__float_as_int(F0) >> 23) & 0xFF) - 127;
            e0 = (F0 > 0.0f) ? e0 : 0;
            F0 = ldexpf(F0, -e0);
            M0 += e0;

            int Ml = __shfl_up(M, 1, 64);
            int dl = lane0 ? (M0 - M) : (Ml - M);
            int dlc = dl > 0 ? dl : 0;               // down-only self-squash
#pragma unroll
            for (int i = 0; i < 8; ++i) F[i] = ldexpf(F[i], -dlc);
            M += dlc;
            int dn = Ml - M; dn = dn > 0 ? 0 : dn;
            int d0 = M0 - M; d0 = d0 > 0 ? 0 : d0;
            sA  = ldexpf(1.0f, dn);
            sf0 = ldexpf(1.0f, d0);
            Fl = __shfl_up(F[7], 1, 64);             // post-squash neighbor value

            // ---- 8 steps ----
            do_step(ga, gb); do_step(gb, ga);
            do_step(ga, gb); do_step(gb, ga);
            do_step(ga, gb); do_step(gb, ga);
            do_step(ga, gb); do_step(gb, ga);
        }
    }

    // ---- epilogue: log2 reconstruction (denormal-safe) ----
#pragma unroll
    for (int i = 0; i < 8; ++i) {
        float v = fmaxf(F[i] * 16777216.0f, 1e-38f);
        garr[8 * l + 1 + i] = __log2f(v) - 24.0f + (float)M;
    }
    if (lane0) {
        float v0 = fmaxf(F0 * 16777216.0f, 1e-38f);
        garr[0] = __log2f(v0) - 24.0f + (float)M0;
    }
    __syncthreads();
    if (lane0) {
        int sl = seqlens[b];
        out[b] = -(garr[sl] * LN2F) / (float)TT;
    }
}

extern "C" void kernel_launch(void* const* d_in, const int* in_sizes, int n_in,
                              void* d_out, int out_size, void* d_ws, size_t ws_size,
                              hipStream_t stream) {
    const float* x       = (const float*)d_in[0];
    const int*   seqs    = (const int*)d_in[1];
    const int*   seqlens = (const int*)d_in[2];
    float*       out     = (float*)d_out;
    float*       xT      = (float*)d_ws;             // BB*TT*8 floats = 8 MB

    int n = TT * BB * 5;
    ctc_prepass<<<(n + 255) / 256, 256, 0, stream>>>(x, xT);
    ctc_scan<<<BB, 64, 0, stream>>>(xT, seqs, seqlens, out);
}